// Round 3
// baseline (266.950 us; speedup 1.0000x reference)
//
#include <hip/hip_runtime.h>
#include <math.h>

// x = (B=4, S=8192, D=1024) float32.
// out[b,s,d] = x[b,s,d] + pos[s,d]
//   pos[s,d] = sin(s / 10000^((d+1)/D)) if d even else cos(...)
#define PE_S 8192
#define PE_D 1024
#define PE_B 4

typedef float v4f __attribute__((ext_vector_type(4)));  // native clang vector:
// required by __builtin_nontemporal_store (HIP_vector_type float4 is rejected).

// One thread per (s, 8-consecutive-d). Position values computed ONCE per
// thread with HW v_exp/v_sin/v_cos (input in revolutions, explicit fract
// range reduction -- phase error ~5e-4 rad, threshold is 0.124), then 4
// batch planes of 2x float4 load/add/store.
// Stores are non-temporal: `out` is write-only, and keeping it out of the
// 256 MiB L3 lets x (128 MiB) stay fully L3-resident across dispatches
// (R1 counters: FETCH was only half of x -> write stream was thrashing it).
__global__ __launch_bounds__(256) void position_encoder_kernel(
    const float* __restrict__ x, float* __restrict__ out) {
    const int tid = blockIdx.x * blockDim.x + threadIdx.x;  // 0 .. S*D/8-1
    const int oct = tid & (PE_D / 8 - 1);                   // 0..127
    const int s   = tid >> 7;                               // 0..8191
    const int d0  = oct << 3;                               // octet start (even)

    const float fs = (float)s;
    // phase(s,j) = s / 10000^((j+1)/D) radians
    //            = s * 2^((j+1)*a2 + c2) revolutions
    const float a2 = -0.012976281620653760f;  // -log2(10000)/1024
    const float c2 = -2.6514961294723187f;    // -log2(2*pi)

    float p[8];
#pragma unroll
    for (int k = 0; k < 8; k += 2) {
        // d0+k even -> sin, d0+k+1 odd -> cos
        const float we = __builtin_amdgcn_exp2f((float)(d0 + k + 1) * a2 + c2);
        const float wo = __builtin_amdgcn_exp2f((float)(d0 + k + 2) * a2 + c2);
        float te = fs * we;  te -= floorf(te);   // fract -> [0,1) revolutions
        float to = fs * wo;  to -= floorf(to);
        p[k]     = __builtin_amdgcn_sinf(te);    // sin(te * 2*pi)
        p[k + 1] = __builtin_amdgcn_cosf(to);    // cos(to * 2*pi)
    }

    const v4f pe0 = {p[0], p[1], p[2], p[3]};
    const v4f pe1 = {p[4], p[5], p[6], p[7]};

    const size_t base  = (size_t)s * PE_D + (size_t)d0;
    const size_t plane = (size_t)PE_S * PE_D;
#pragma unroll
    for (int b = 0; b < PE_B; ++b) {
        const v4f* xp = reinterpret_cast<const v4f*>(x + (size_t)b * plane + base);
        v4f* op       = reinterpret_cast<v4f*>(out + (size_t)b * plane + base);
        const v4f v0 = xp[0];
        const v4f v1 = xp[1];
        __builtin_nontemporal_store(v0 + pe0, op);
        __builtin_nontemporal_store(v1 + pe1, op + 1);
    }
}

extern "C" void kernel_launch(void* const* d_in, const int* in_sizes, int n_in,
                              void* d_out, int out_size, void* d_ws, size_t ws_size,
                              hipStream_t stream) {
    const float* x = (const float*)d_in[0];
    float* out = (float*)d_out;

    const int threads = 256;
    const int total = PE_S * (PE_D / 8);       // 1,048,576 threads
    const int blocks = total / threads;        // 4096 blocks
    position_encoder_kernel<<<blocks, threads, 0, stream>>>(x, out);
}

// Round 4
// 232.852 us; speedup vs baseline: 1.1464x; 1.1464x over previous
//
#include <hip/hip_runtime.h>
#include <math.h>

// x = (B=4, S=8192, D=1024) float32.
// out[b,s,d] = x[b,s,d] + pos[s,d]
//   pos[s,d] = sin(s / 10000^((d+1)/D)) if d even else cos(...)
#define PE_S 8192
#define PE_D 1024
#define PE_B 4

typedef float v4f __attribute__((ext_vector_type(4)));

// One thread per (s, 8-consecutive-d), 4 batch planes.
// R3 lesson: nontemporal stores amplified WRITE_SIZE 1.7x (131->224 MB) and
// regressed 86->113 us -> normal stores only.
// R1 lesson: per-batch load->store loop kept only ~2 loads in flight
// (VGPR_Count 24-28) -> latency-bound at 2.3 TB/s. This version issues all
// 8 global_load_dwordx4 before any store (explicit register batch), with
// __launch_bounds__(256,8) keeping 8 waves/SIMD at ~48 VGPRs.
__global__ __launch_bounds__(256, 8) void position_encoder_kernel(
    const float* __restrict__ x, float* __restrict__ out) {
    const int tid = blockIdx.x * blockDim.x + threadIdx.x;  // 0 .. S*D/8-1
    const int oct = tid & (PE_D / 8 - 1);                   // 0..127
    const int s   = tid >> 7;                               // 0..8191
    const int d0  = oct << 3;                               // octet start (even)

    const size_t base  = (size_t)s * PE_D + (size_t)d0;
    const size_t plane = (size_t)PE_S * PE_D;

    // ---- issue ALL loads first: 8 outstanding global_load_dwordx4 ----
    v4f v[2 * PE_B];
#pragma unroll
    for (int b = 0; b < PE_B; ++b) {
        const v4f* xp = reinterpret_cast<const v4f*>(x + (size_t)b * plane + base);
        v[2 * b]     = xp[0];
        v[2 * b + 1] = xp[1];
    }

    // ---- position values via HW exp2/sin/cos (overlaps load latency) ----
    // phase(s,j) = s / 10000^((j+1)/D) radians = s * 2^((j+1)*a2 + c2) rev
    const float fs = (float)s;
    const float a2 = -0.012976281620653760f;  // -log2(10000)/1024
    const float c2 = -2.6514961294723187f;    // -log2(2*pi)

    float p[8];
#pragma unroll
    for (int k = 0; k < 8; k += 2) {
        const float we = __builtin_amdgcn_exp2f((float)(d0 + k + 1) * a2 + c2);
        const float wo = __builtin_amdgcn_exp2f((float)(d0 + k + 2) * a2 + c2);
        float te = fs * we;  te -= floorf(te);   // fract -> [0,1) revolutions
        float to = fs * wo;  to -= floorf(to);
        p[k]     = __builtin_amdgcn_sinf(te);    // sin(2*pi*te), d even
        p[k + 1] = __builtin_amdgcn_cosf(to);    // cos(2*pi*to), d odd
    }
    const v4f pe0 = {p[0], p[1], p[2], p[3]};
    const v4f pe1 = {p[4], p[5], p[6], p[7]};

    // ---- add + store ----
#pragma unroll
    for (int b = 0; b < PE_B; ++b) {
        v4f* op = reinterpret_cast<v4f*>(out + (size_t)b * plane + base);
        op[0] = v[2 * b] + pe0;
        op[1] = v[2 * b + 1] + pe1;
    }
}

extern "C" void kernel_launch(void* const* d_in, const int* in_sizes, int n_in,
                              void* d_out, int out_size, void* d_ws, size_t ws_size,
                              hipStream_t stream) {
    const float* x = (const float*)d_in[0];
    float* out = (float*)d_out;

    const int threads = 256;
    const int total = PE_S * (PE_D / 8);       // 1,048,576 threads
    const int blocks = total / threads;        // 4096 blocks
    position_encoder_kernel<<<blocks, threads, 0, stream>>>(x, out);
}